// Round 5
// baseline (200.832 us; speedup 1.0000x reference)
//
#include <hip/hip_runtime.h>
#include <math.h>

// CapsuleLayer dynamic routing. C=32,B=32,N=4096,IN=16,OUT=32, 3 iters.
// v13: fused persistent kernel, per-c hierarchical sync, coalesced reduce.
// v12 diagnosis (rocprof): (a) timed path STILL fell back to v9 (200.685 ==
// v9) -> ctor probe fails at dlopen and the occupancy API is prohibited under
// strict graph capture; gate now DEFAULTS TO MEGA unless the probe gives a
// definitive negative (co-residency at 4 blk/CU is guaranteed by
// __launch_bounds__(256,4): 64 VGPR, 22KB LDS, and proven by v11/v12 runs).
// (b) k_mega2 = 700us with VALUBusy 3.9%: the REDUNDANT reduce (1024 blocks
// x 33.8K uncoalesced sc1 dword loads = ~8.7M half-used L3 transactions)
// costs ~550us. v13: ONE reducer block per c does a coalesced u64 reduce
// (32 x 135KB total), publishes CV[c] + per-c flag; 31 peers spin on their
// own c's flag line (32 lines, no hot-line storm) and load CV coalesced.
// No acquires anywhere -> L2 never invalidated -> Wt stays cached.
// Sweep bodies and the release-fence protocol are unchanged (v11-proven).

typedef _Float16 f16x8 __attribute__((ext_vector_type(8)));
typedef float f32x16 __attribute__((ext_vector_type(16)));

namespace {
constexpr int kC = 32, kB = 32, kN = 4096, kI = 16, kD = 32;
constexpr int CHUNKS = 32;            // n-chunks per c
constexpr int CHUNK_N = kN / CHUNKS;  // 128
constexpr int PS = kB * kD + kB;      // 1056 floats per (c,chunk) partial
constexpr int GRID = kC * CHUNKS;     // 1024 blocks
constexpr size_t XT_ELEMS = (size_t)kN * kB * kI;       // f16 [n][b][i]
constexpr size_t WT_ELEMS = (size_t)kC * kN * kI * kD;  // f16 fragment layout
constexpr size_t P_FLOATS = (size_t)kC * CHUNKS * PS;
constexpr size_t CV_FLOATS = (size_t)kC * kB * kD;
constexpr int BAR_U32 = 2048;  // [c*32]: arrivals; [1024+c*32]: cv flags
constexpr size_t WS_BYTES_MID = XT_ELEMS * 2 + (P_FLOATS + CV_FLOATS) * 4;
constexpr size_t WS_BYTES_BIG =
    (XT_ELEMS + WT_ELEMS) * 2 + (P_FLOATS + CV_FLOATS) * 4;
constexpr size_t WS_BYTES_MEGA =
    (XT_ELEMS + WT_ELEMS) * 2 + (P_FLOATS + CV_FLOATS) * 4 + BAR_U32 * 4 + 256;
}  // namespace

__device__ __forceinline__ f32x16 zero16() {
  f32x16 z;
#pragma unroll
  for (int r = 0; r < 16; ++r) z[r] = 0.f;
  return z;
}

// ---- k_xt: x[b][n][i] f32 -> xt[n][b][i] f16; also zeroes barrier ctrs ----
__global__ __launch_bounds__(256) void k_xt(const float* __restrict__ x,
                                            _Float16* __restrict__ xt,
                                            unsigned* __restrict__ bar) {
  if (bar && blockIdx.x == 0)
    for (int i = threadIdx.x; i < BAR_U32; i += 256) bar[i] = 0u;
  const int t = blockIdx.x * 256 + threadIdx.x;  // [0, 262144) == 2*B*N
  const int r = t >> 1, half = t & 1;            // r = b*4096 + n
  const int b = r >> 12, n = r & 4095;
  const float4* s4 =
      reinterpret_cast<const float4*>(x) + (size_t)r * 4 + half * 2;
  const float4 f0 = s4[0], f1 = s4[1];
  f16x8 o;
  o[0] = (_Float16)f0.x; o[1] = (_Float16)f0.y;
  o[2] = (_Float16)f0.z; o[3] = (_Float16)f0.w;
  o[4] = (_Float16)f1.x; o[5] = (_Float16)f1.y;
  o[6] = (_Float16)f1.z; o[7] = (_Float16)f1.w;
  *reinterpret_cast<f16x8*>(xt + ((size_t)n * kB + b) * kI + half * 8) = o;
}

// ---- per-c sync primitives (release arrivals, relaxed spin, no acquires) --
__device__ __forceinline__ void group_arrive(unsigned* ctr, int tid) {
  __threadfence();   // wbL2: publish this block's plain stores (P) to L3
  __syncthreads();   // all threads fenced
  if (tid == 0)
    __hip_atomic_fetch_add(ctr, 1u, __ATOMIC_RELEASE,
                           __HIP_MEMORY_SCOPE_AGENT);
}

__device__ __forceinline__ void spin_ge(unsigned* addr, unsigned target) {
  while (__hip_atomic_load(addr, __ATOMIC_RELAXED,
                           __HIP_MEMORY_SCOPE_AGENT) < target)
    __builtin_amdgcn_s_sleep(2);
}

__device__ __forceinline__ float ld_f32_agent(const float* p) {
  return __hip_atomic_load(p, __ATOMIC_RELAXED, __HIP_MEMORY_SCOPE_AGENT);
}
__device__ __forceinline__ unsigned long long ld_u64_agent(const float* p) {
  return __hip_atomic_load(reinterpret_cast<const unsigned long long*>(p),
                           __ATOMIC_RELAXED, __HIP_MEMORY_SCOPE_AGENT);
}

// ================= fused-kernel phase bodies ===============================

// Sweep 0: MODE 0 (uniform probs, acc in MFMA C) + EMIT Wt f16 fragments.
__device__ __forceinline__ void mega_sweep0(const float* __restrict__ W,
                                            const _Float16* __restrict__ xt,
                                            _Float16* __restrict__ Wt,
                                            float* __restrict__ P,
                                            float (*red)[32][33], int c,
                                            int chunk, int tid) {
  const int w = tid >> 6, l = tid & 63;
  const int m = l & 31, h = l >> 5;
  const int n0 = chunk * CHUNK_N;
  constexpr int TILES = CHUNK_N / 4;

  const float* wp = W + ((size_t)c * kN + n0 + w) * 512 + (h * 8) * 32 + m;
  const _Float16* xp = xt + ((size_t)(n0 + w)) * 512 + m * 16 + h * 8;
  _Float16* wtp = Wt + ((size_t)c * kN + n0 + w) * 512 + (size_t)l * 8;

  f32x16 accA = zero16(), accB = zero16();

  float rA0[8], rA1[8];
  f16x8 B0, B1;
#pragma unroll
  for (int j = 0; j < 8; ++j) rA0[j] = __builtin_nontemporal_load(wp + j * 32);
  B0 = *reinterpret_cast<const f16x8*>(xp);
#pragma unroll
  for (int j = 0; j < 8; ++j)
    rA1[j] = __builtin_nontemporal_load(wp + 2048 + j * 32);
  B1 = *reinterpret_cast<const f16x8*>(xp + 2048);

#pragma unroll 1
  for (int t = 0; t < TILES; t += 2) {
    {
      f16x8 a;
#pragma unroll
      for (int j = 0; j < 8; ++j) a[j] = (_Float16)rA0[j];
      const f16x8 b = B0;
      const int tn = (t + 2 < TILES) ? t + 2 : 0;
#pragma unroll
      for (int j = 0; j < 8; ++j)
        rA0[j] = __builtin_nontemporal_load(wp + (size_t)tn * 2048 + j * 32);
      B0 = *reinterpret_cast<const f16x8*>(xp + (size_t)tn * 2048);
      *reinterpret_cast<f16x8*>(wtp + (size_t)t * 2048) = a;
      accA = __builtin_amdgcn_mfma_f32_32x32x16_f16(a, b, accA, 0, 0, 0);
    }
    {
      f16x8 a;
#pragma unroll
      for (int j = 0; j < 8; ++j) a[j] = (_Float16)rA1[j];
      const f16x8 b = B1;
      const int tn = (t + 3 < TILES) ? t + 3 : 0;
#pragma unroll
      for (int j = 0; j < 8; ++j)
        rA1[j] = __builtin_nontemporal_load(wp + (size_t)tn * 2048 + j * 32);
      B1 = *reinterpret_cast<const f16x8*>(xp + (size_t)tn * 2048);
      *reinterpret_cast<f16x8*>(wtp + (size_t)(t + 1) * 2048) = a;
      accB = __builtin_amdgcn_mfma_f32_32x32x16_f16(a, b, accB, 0, 0, 0);
    }
  }
#pragma unroll
  for (int r = 0; r < 16; ++r) accA[r] += accB[r];

#pragma unroll
  for (int r = 0; r < 16; ++r)
    red[w][(r & 3) + 8 * (r >> 2) + 4 * h][m] = accA[r];
  __syncthreads();

  float* Pp = P + ((size_t)c * CHUNKS + chunk) * PS;
#pragma unroll
  for (int e = tid; e < 1024; e += 256) {
    const int d = e >> 5, bb = e & 31;
    Pp[e] = red[0][d][bb] + red[1][d][bb] + red[2][d][bb] + red[3][d][bb];
  }
}

// MODE-1 sweep over Wt f16 fragments; CV comes from LDS (sCV[b][d]).
__device__ __forceinline__ void mega_sweep_wt(
    const _Float16* __restrict__ Wt, const _Float16* __restrict__ xt,
    const float (*sCV)[32], float* __restrict__ P, float (*red)[32][33],
    float (*lred)[32], int c, int chunk, int tid) {
  const int w = tid >> 6, l = tid & 63;
  const int m = l & 31, h = l >> 5;
  const int n0 = chunk * CHUNK_N;
  constexpr int TILES = CHUNK_N / 4;

  const _Float16* wp = Wt + ((size_t)c * kN + n0 + w) * 512 + (size_t)l * 8;
  const _Float16* xp = xt + ((size_t)(n0 + w)) * 512 + m * 16 + h * 8;

  float cvr[16];
#pragma unroll
  for (int r = 0; r < 16; ++r)
    cvr[r] = sCV[m][(r & 3) + 8 * (r >> 2) + 4 * h];

  f32x16 accA = zero16(), accB = zero16();
  float lacc = 0.f;
  const f32x16 z = zero16();

  f16x8 A0, A1, B0, B1;
  A0 = *reinterpret_cast<const f16x8*>(wp);
  B0 = *reinterpret_cast<const f16x8*>(xp);
  A1 = *reinterpret_cast<const f16x8*>(wp + 2048);
  B1 = *reinterpret_cast<const f16x8*>(xp + 2048);

#pragma unroll 1
  for (int t = 0; t < TILES; t += 2) {
    {
      const f16x8 a = A0;
      const f16x8 b = B0;
      const int tn = (t + 2 < TILES) ? t + 2 : 0;
      A0 = *reinterpret_cast<const f16x8*>(wp + (size_t)tn * 2048);
      B0 = *reinterpret_cast<const f16x8*>(xp + (size_t)tn * 2048);
      const f32x16 pr =
          __builtin_amdgcn_mfma_f32_32x32x16_f16(a, b, z, 0, 0, 0);
      float d0 = pr[0] * cvr[0], d1 = pr[1] * cvr[1];
      float d2 = pr[2] * cvr[2], d3 = pr[3] * cvr[3];
#pragma unroll
      for (int r = 4; r < 16; r += 4) {
        d0 = fmaf(pr[r + 0], cvr[r + 0], d0);
        d1 = fmaf(pr[r + 1], cvr[r + 1], d1);
        d2 = fmaf(pr[r + 2], cvr[r + 2], d2);
        d3 = fmaf(pr[r + 3], cvr[r + 3], d3);
      }
      float dp = (d0 + d1) + (d2 + d3);
      dp += __shfl_xor(dp, 32);
      const float e = __expf(dp);
      lacc += e;
#pragma unroll
      for (int r = 0; r < 16; ++r) accA[r] = fmaf(e, pr[r], accA[r]);
    }
    {
      const f16x8 a = A1;
      const f16x8 b = B1;
      const int tn = (t + 3 < TILES) ? t + 3 : 0;
      A1 = *reinterpret_cast<const f16x8*>(wp + (size_t)tn * 2048);
      B1 = *reinterpret_cast<const f16x8*>(xp + (size_t)tn * 2048);
      const f32x16 pr =
          __builtin_amdgcn_mfma_f32_32x32x16_f16(a, b, z, 0, 0, 0);
      float d0 = pr[0] * cvr[0], d1 = pr[1] * cvr[1];
      float d2 = pr[2] * cvr[2], d3 = pr[3] * cvr[3];
#pragma unroll
      for (int r = 4; r < 16; r += 4) {
        d0 = fmaf(pr[r + 0], cvr[r + 0], d0);
        d1 = fmaf(pr[r + 1], cvr[r + 1], d1);
        d2 = fmaf(pr[r + 2], cvr[r + 2], d2);
        d3 = fmaf(pr[r + 3], cvr[r + 3], d3);
      }
      float dp = (d0 + d1) + (d2 + d3);
      dp += __shfl_xor(dp, 32);
      const float e = __expf(dp);
      lacc += e;
#pragma unroll
      for (int r = 0; r < 16; ++r) accB[r] = fmaf(e, pr[r], accB[r]);
    }
  }
#pragma unroll
  for (int r = 0; r < 16; ++r) accA[r] += accB[r];

#pragma unroll
  for (int r = 0; r < 16; ++r)
    red[w][(r & 3) + 8 * (r >> 2) + 4 * h][m] = accA[r];
  if (h == 0) lred[w][m] = lacc;
  __syncthreads();

  float* Pp = P + ((size_t)c * CHUNKS + chunk) * PS;
#pragma unroll
  for (int e = tid; e < 1024; e += 256) {
    const int d = e >> 5, bb = e & 31;
    Pp[e] = red[0][d][bb] + red[1][d][bb] + red[2][d][bb] + red[3][d][bb];
  }
  if (tid < 32)
    Pp[1024 + tid] = lred[0][tid] + lred[1][tid] + lred[2][tid] + lred[3][tid];
}

// Reducer-side (one block per c) COALESCED reduce over chunks + squash.
// Thread t owns P-elements e = {2t, 2t+1, 512+2t, 512+2t+1} (e = d*32+b):
// (d0,b0),(d0,b0+1),(d0+16,b0),(d0+16,b0+1), d0=t>>4, b0=2*(t&15).
// K<2: update cvrun, write CVc[b*32+d]. K==2: write out.
template <int K>
__device__ __forceinline__ void red_reduce(const float* __restrict__ P,
                                           float* __restrict__ CVc,
                                           float* __restrict__ out,
                                           float (&cvrun)[4],
                                           float (*ldsSn)[16][2],
                                           float* ldsCoef, float* ldsInv,
                                           int c, int tid) {
  const float* Pc = P + (size_t)c * CHUNKS * PS;
  const int hb = tid & 15;
  const int b0 = hb * 2;
  const int d0 = tid >> 4;
  float s0 = 0.f, s1 = 0.f, s2 = 0.f, s3 = 0.f;
#pragma unroll 4
  for (int ch = 0; ch < CHUNKS; ++ch) {
    const float* base = Pc + (size_t)ch * PS;
    const unsigned long long q0 = ld_u64_agent(base + 2 * tid);
    const unsigned long long q1 = ld_u64_agent(base + 512 + 2 * tid);
    s0 += __uint_as_float((unsigned)q0);
    s1 += __uint_as_float((unsigned)(q0 >> 32));
    s2 += __uint_as_float((unsigned)q1);
    s3 += __uint_as_float((unsigned)(q1 >> 32));
  }
  float inv0, inv1;
  if constexpr (K == 0) {
    inv0 = inv1 = 1.0f / (float)kN;
  } else {
    if (tid < 32) {
      float lb = 0.f;
#pragma unroll 4
      for (int ch = 0; ch < CHUNKS; ++ch)
        lb += ld_f32_agent(Pc + (size_t)ch * PS + 1024 + tid);
      ldsInv[tid] = 1.0f / lb;
    }
    __syncthreads();
    inv0 = ldsInv[b0];
    inv1 = ldsInv[b0 + 1];
  }
  const float v0 = s0 * inv0, v1 = s1 * inv1;
  const float v2 = s2 * inv0, v3 = s3 * inv1;
  float snA = v0 * v0 + v2 * v2;  // b0 partial over {d0, d0+16}
  float snB = v1 * v1 + v3 * v3;  // b0+1
  snA += __shfl_xor(snA, 16); snA += __shfl_xor(snA, 32);
  snB += __shfl_xor(snB, 16); snB += __shfl_xor(snB, 32);
  if ((tid & 63) < 16) {
    ldsSn[tid >> 6][hb][0] = snA;
    ldsSn[tid >> 6][hb][1] = snB;
  }
  __syncthreads();
  if (tid < 16) {
    const float sA = ldsSn[0][tid][0] + ldsSn[1][tid][0] + ldsSn[2][tid][0] +
                     ldsSn[3][tid][0];
    const float sB = ldsSn[0][tid][1] + ldsSn[1][tid][1] + ldsSn[2][tid][1] +
                     ldsSn[3][tid][1];
    ldsCoef[2 * tid] = sqrtf(sA) / (1.0f + sA);
    ldsCoef[2 * tid + 1] = sqrtf(sB) / (1.0f + sB);
  }
  __syncthreads();
  const float c0 = ldsCoef[b0], c1 = ldsCoef[b0 + 1];
  if constexpr (K == 2) {
    float* oc = out + (size_t)c * 1024;
    oc[b0 * 32 + d0] = v0 * c0;
    oc[(b0 + 1) * 32 + d0] = v1 * c1;
    oc[b0 * 32 + d0 + 16] = v2 * c0;
    oc[(b0 + 1) * 32 + d0 + 16] = v3 * c1;
  } else {
    if constexpr (K == 0) {
      cvrun[0] = v0 * c0; cvrun[1] = v1 * c1;
      cvrun[2] = v2 * c0; cvrun[3] = v3 * c1;
    } else {
      cvrun[0] += v0 * c0; cvrun[1] += v1 * c1;
      cvrun[2] += v2 * c0; cvrun[3] += v3 * c1;
    }
    CVc[b0 * 32 + d0] = cvrun[0];
    CVc[(b0 + 1) * 32 + d0] = cvrun[1];
    CVc[b0 * 32 + d0 + 16] = cvrun[2];
    CVc[(b0 + 1) * 32 + d0 + 16] = cvrun[3];
  }
}

// Coalesced CV[c] -> sCV load via agent-scope u64 loads (L2-bypassing).
__device__ __forceinline__ void load_cv(const float* __restrict__ CVc,
                                        float (*sCV)[32], int tid) {
#pragma unroll
  for (int q = 0; q < 2; ++q) {
    const int e = 2 * tid + 512 * q;  // e = b*32+d, even
    const unsigned long long v = ld_u64_agent(CVc + e);
    sCV[e >> 5][e & 31] = __uint_as_float((unsigned)v);
    sCV[e >> 5][(e & 31) + 1] = __uint_as_float((unsigned)(v >> 32));
  }
  __syncthreads();
}

__global__ __launch_bounds__(256, 4) void k_mega3(
    const float* __restrict__ W, const _Float16* __restrict__ xt,
    _Float16* __restrict__ Wt, float* __restrict__ P, float* __restrict__ CVg,
    unsigned* __restrict__ bar, float* __restrict__ out) {
  __shared__ float red[4][32][33];
  __shared__ float lred[4][32];
  __shared__ float sCV[32][32];
  __shared__ float ldsSn[4][16][2];
  __shared__ float ldsCoef[32];
  __shared__ float ldsInv[32];
  const int bid = blockIdx.x;
  const int c = bid & 31;  // same-c blocks share an XCD slot pattern
  const int chunk = bid >> 5;
  const int tid = threadIdx.x;
  unsigned* barc = bar + c * 32;          // arrival counter (own 128B line)
  unsigned* cvf = bar + 1024 + c * 32;    // CV publish flag (own 128B line)
  float* CVc = CVg + (size_t)c * 1024;
  float cvrun[4] = {0.f, 0.f, 0.f, 0.f};

  // ---- iter 1: sweep0 (W nt -> Wt, P), reduce by chunk-0 block ----
  mega_sweep0(W, xt, Wt, P, red, c, chunk, tid);
  group_arrive(barc, tid);
  if (chunk == 0) {
    if (tid == 0) spin_ge(barc, 32);
    __syncthreads();
    red_reduce<0>(P, CVc, nullptr, cvrun, ldsSn, ldsCoef, ldsInv, c, tid);
    __threadfence();       // publish CV stores
    __syncthreads();
    if (tid == 0)
      __hip_atomic_fetch_add(cvf, 1u, __ATOMIC_RELEASE,
                             __HIP_MEMORY_SCOPE_AGENT);
  }
  if (tid == 0) spin_ge(cvf, 1);
  __syncthreads();
  load_cv(CVc, sCV, tid);

  // ---- iter 2 ----
  mega_sweep_wt(Wt, xt, sCV, P, red, lred, c, chunk, tid);
  group_arrive(barc, tid);
  if (chunk == 0) {
    if (tid == 0) spin_ge(barc, 64);
    __syncthreads();
    red_reduce<1>(P, CVc, nullptr, cvrun, ldsSn, ldsCoef, ldsInv, c, tid);
    __threadfence();
    __syncthreads();
    if (tid == 0)
      __hip_atomic_fetch_add(cvf, 1u, __ATOMIC_RELEASE,
                             __HIP_MEMORY_SCOPE_AGENT);
  }
  if (tid == 0) spin_ge(cvf, 2);
  __syncthreads();
  load_cv(CVc, sCV, tid);

  // ---- iter 3: sweep + final squash -> out ----
  mega_sweep_wt(Wt, xt, sCV, P, red, lred, c, chunk, tid);
  group_arrive(barc, tid);
  if (chunk == 0) {
    if (tid == 0) spin_ge(barc, 96);
    __syncthreads();
    red_reduce<2>(P, nullptr, out, cvrun, ldsSn, ldsCoef, ldsInv, c, tid);
  }
}

// ================= v9 fallback kernels (proven 201us) ======================

template <int MODE, bool EMIT>
__global__ __launch_bounds__(256) void k_sweep(const float* __restrict__ W,
                                               const _Float16* __restrict__ xt,
                                               const float* __restrict__ cumVec,
                                               float* __restrict__ partials,
                                               _Float16* __restrict__ Wt) {
  __shared__ float red[4][32][33];
  __shared__ float lred[4][32];
  const int bid = blockIdx.x;
  const int c = bid & 31;
  const int chunk = bid >> 5;
  const int tid = threadIdx.x;
  const int w = tid >> 6, l = tid & 63;
  const int m = l & 31, h = l >> 5;
  const int n0 = chunk * CHUNK_N;
  constexpr int TILES = CHUNK_N / 4;

  const float* wp = W + ((size_t)c * kN + n0 + w) * 512 + (h * 8) * 32 + m;
  const _Float16* xp = xt + ((size_t)(n0 + w)) * 512 + m * 16 + h * 8;
  _Float16* wtp =
      EMIT ? (Wt + ((size_t)c * kN + n0 + w) * 512 + (size_t)l * 8) : nullptr;

  float cvr[16];
  if (MODE) {
    const float* cvp = cumVec + (size_t)c * 1024 + m * 32;
#pragma unroll
    for (int r = 0; r < 16; ++r) cvr[r] = cvp[(r & 3) + 8 * (r >> 2) + 4 * h];
  }

  f32x16 accA = zero16(), accB = zero16();
  float lacc = 0.f;
  const f32x16 z = zero16();

  float rA0[8], rA1[8];
  f16x8 B0, B1;
#pragma unroll
  for (int j = 0; j < 8; ++j)
    rA0[j] = EMIT ? __builtin_nontemporal_load(wp + j * 32) : wp[j * 32];
  B0 = *reinterpret_cast<const f16x8*>(xp);
#pragma unroll
  for (int j = 0; j < 8; ++j)
    rA1[j] = EMIT ? __builtin_nontemporal_load(wp + 2048 + j * 32)
                  : wp[2048 + j * 32];
  B1 = *reinterpret_cast<const f16x8*>(xp + 2048);

#pragma unroll 1
  for (int t = 0; t < TILES; t += 2) {
    {
      f16x8 a;
#pragma unroll
      for (int j = 0; j < 8; ++j) a[j] = (_Float16)rA0[j];
      const f16x8 b = B0;
      const int tn = (t + 2 < TILES) ? t + 2 : 0;
#pragma unroll
      for (int j = 0; j < 8; ++j)
        rA0[j] = EMIT ? __builtin_nontemporal_load(wp + (size_t)tn * 2048 +
                                                   j * 32)
                      : wp[(size_t)tn * 2048 + j * 32];
      B0 = *reinterpret_cast<const f16x8*>(xp + (size_t)tn * 2048);
      if constexpr (EMIT)
        *reinterpret_cast<f16x8*>(wtp + (size_t)t * 2048) = a;
      if constexpr (MODE == 0) {
        accA = __builtin_amdgcn_mfma_f32_32x32x16_f16(a, b, accA, 0, 0, 0);
      } else {
        const f32x16 pr =
            __builtin_amdgcn_mfma_f32_32x32x16_f16(a, b, z, 0, 0, 0);
        float d0 = pr[0] * cvr[0], d1 = pr[1] * cvr[1];
        float d2 = pr[2] * cvr[2], d3 = pr[3] * cvr[3];
#pragma unroll
        for (int r = 4; r < 16; r += 4) {
          d0 = fmaf(pr[r + 0], cvr[r + 0], d0);
          d1 = fmaf(pr[r + 1], cvr[r + 1], d1);
          d2 = fmaf(pr[r + 2], cvr[r + 2], d2);
          d3 = fmaf(pr[r + 3], cvr[r + 3], d3);
        }
        float dp = (d0 + d1) + (d2 + d3);
        dp += __shfl_xor(dp, 32);
        const float e = __expf(dp);
        lacc += e;
#pragma unroll
        for (int r = 0; r < 16; ++r) accA[r] = fmaf(e, pr[r], accA[r]);
      }
    }
    {
      f16x8 a;
#pragma unroll
      for (int j = 0; j < 8; ++j) a[j] = (_Float16)rA1[j];
      const f16x8 b = B1;
      const int tn = (t + 3 < TILES) ? t + 3 : 0;
#pragma unroll
      for (int j = 0; j < 8; ++j)
        rA1[j] = EMIT ? __builtin_nontemporal_load(wp + (size_t)tn * 2048 +
                                                   j * 32)
                      : wp[(size_t)tn * 2048 + j * 32];
      B1 = *reinterpret_cast<const f16x8*>(xp + (size_t)tn * 2048);
      if constexpr (EMIT)
        *reinterpret_cast<f16x8*>(wtp + (size_t)(t + 1) * 2048) = a;
      if constexpr (MODE == 0) {
        accB = __builtin_amdgcn_mfma_f32_32x32x16_f16(a, b, accB, 0, 0, 0);
      } else {
        const f32x16 pr =
            __builtin_amdgcn_mfma_f32_32x32x16_f16(a, b, z, 0, 0, 0);
        float d0 = pr[0] * cvr[0], d1 = pr[1] * cvr[1];
        float d2 = pr[2] * cvr[2], d3 = pr[3] * cvr[3];
#pragma unroll
        for (int r = 4; r < 16; r += 4) {
          d0 = fmaf(pr[r + 0], cvr[r + 0], d0);
          d1 = fmaf(pr[r + 1], cvr[r + 1], d1);
          d2 = fmaf(pr[r + 2], cvr[r + 2], d2);
          d3 = fmaf(pr[r + 3], cvr[r + 3], d3);
        }
        float dp = (d0 + d1) + (d2 + d3);
        dp += __shfl_xor(dp, 32);
        const float e = __expf(dp);
        lacc += e;
#pragma unroll
        for (int r = 0; r < 16; ++r) accB[r] = fmaf(e, pr[r], accB[r]);
      }
    }
  }
#pragma unroll
  for (int r = 0; r < 16; ++r) accA[r] += accB[r];

#pragma unroll
  for (int r = 0; r < 16; ++r)
    red[w][(r & 3) + 8 * (r >> 2) + 4 * h][m] = accA[r];
  if (MODE && h == 0) lred[w][m] = lacc;
  __syncthreads();

  float* Pp = partials + ((size_t)c * CHUNKS + chunk) * PS;
#pragma unroll
  for (int e = tid; e < 1024; e += 256) {
    const int d = e >> 5, bb = e & 31;
    Pp[e] = red[0][d][bb] + red[1][d][bb] + red[2][d][bb] + red[3][d][bb];
  }
  if (MODE && tid < 32)
    Pp[1024 + tid] = lred[0][tid] + lred[1][tid] + lred[2][tid] + lred[3][tid];
}

__global__ __launch_bounds__(256) void k_sweep_wt(
    const _Float16* __restrict__ Wt, const _Float16* __restrict__ xt,
    const float* __restrict__ cumVec, float* __restrict__ partials) {
  __shared__ float red[4][32][33];
  __shared__ float lred[4][32];
  __shared__ float sCV[32][32];
  const int bid = blockIdx.x;
  const int c = bid & 31;
  const int chunk = bid >> 5;
  const int tid = threadIdx.x;
  for (int e = tid; e < 1024; e += 256)
    sCV[e >> 5][e & 31] = cumVec[(size_t)c * 1024 + e];
  __syncthreads();
  mega_sweep_wt(Wt, xt, sCV, partials, red, lred, c, chunk, tid);
}

template <int K>
__global__ __launch_bounds__(1024) void k_reduce(
    const float* __restrict__ partials, float* __restrict__ CV,
    float* __restrict__ out) {
  const int c = blockIdx.x;
  const int t = threadIdx.x;
  const int b = t >> 5, d = t & 31;
  const float* Pc = partials + (size_t)c * CHUNKS * PS;
  float s = 0.f;
#pragma unroll 4
  for (int ch = 0; ch < CHUNKS; ++ch) s += Pc[(size_t)ch * PS + d * 32 + b];
  float inv;
  if constexpr (K == 0) {
    inv = 1.0f / (float)kN;
  } else {
    float lb = 0.f;
#pragma unroll 4
    for (int ch = 0; ch < CHUNKS; ++ch) lb += Pc[(size_t)ch * PS + 1024 + b];
    inv = 1.0f / lb;
  }
  const float sv = s * inv;
  float sn = sv * sv;
  sn += __shfl_xor(sn, 1);
  sn += __shfl_xor(sn, 2);
  sn += __shfl_xor(sn, 4);
  sn += __shfl_xor(sn, 8);
  sn += __shfl_xor(sn, 16);
  const float coef = sqrtf(sn) / (1.0f + sn);
  const float o = sv * coef;
  if constexpr (K == 2)
    out[(size_t)c * 1024 + t] = o;
  else if constexpr (K == 0)
    CV[(size_t)c * 1024 + t] = o;
  else
    CV[(size_t)c * 1024 + t] += o;
}

// ---------------- v1 single-kernel fallback (no ws; passed @~590us) --------
namespace v1 {
constexpr int BG = 4, NSLOT = 128, THREADS1 = NSLOT * 8;
template <int MODE>
__device__ __forceinline__ void sweep_pass(const float* __restrict__ Wc,
                                           const float* __restrict__ x, int b0,
                                           int tid, int nslot, int dg,
                                           float (*red)[8][20], float (*sS)[kD],
                                           float* sL, const float (*sVec)[kD]) {
  float acc[BG][4];
  float lv[BG];
#pragma unroll
  for (int b = 0; b < BG; ++b) {
    lv[b] = 0.f;
#pragma unroll
    for (int j = 0; j < 4; ++j) acc[b][j] = 0.f;
  }
  float vec[BG][4];
  if (MODE) {
#pragma unroll
    for (int b = 0; b < BG; ++b)
#pragma unroll
      for (int j = 0; j < 4; ++j) vec[b][j] = sVec[b][4 * dg + j];
  }
#pragma unroll 1
  for (int n = nslot; n < kN; n += NSLOT) {
    const float* Wn = Wc + (size_t)n * (kI * kD) + 4 * dg;
    float pr[BG][4];
#pragma unroll
    for (int b = 0; b < BG; ++b)
#pragma unroll
      for (int j = 0; j < 4; ++j) pr[b][j] = 0.f;
#pragma unroll
    for (int iq = 0; iq < 4; ++iq) {
      float4 wv[4];
#pragma unroll
      for (int r = 0; r < 4; ++r)
        wv[r] = *reinterpret_cast<const float4*>(Wn + (4 * iq + r) * kD);
#pragma unroll
      for (int b = 0; b < BG; ++b) {
        const float4 xv = *reinterpret_cast<const float4*>(
            x + ((size_t)(b0 + b) * kN + n) * kI + 4 * iq);
        const float xsv[4] = {xv.x, xv.y, xv.z, xv.w};
#pragma unroll
        for (int r = 0; r < 4; ++r) {
          pr[b][0] = fmaf(xsv[r], wv[r].x, pr[b][0]);
          pr[b][1] = fmaf(xsv[r], wv[r].y, pr[b][1]);
          pr[b][2] = fmaf(xsv[r], wv[r].z, pr[b][2]);
          pr[b][3] = fmaf(xsv[r], wv[r].w, pr[b][3]);
        }
      }
    }
    if (MODE == 0) {
#pragma unroll
      for (int b = 0; b < BG; ++b)
#pragma unroll
        for (int j = 0; j < 4; ++j) acc[b][j] += pr[b][j];
    } else {
#pragma unroll
      for (int b = 0; b < BG; ++b) {
        float dp = pr[b][0] * vec[b][0] + pr[b][1] * vec[b][1] +
                   pr[b][2] * vec[b][2] + pr[b][3] * vec[b][3];
        dp += __shfl_xor(dp, 1);
        dp += __shfl_xor(dp, 2);
        dp += __shfl_xor(dp, 4);
        const float e = __expf(dp);
        lv[b] += e;
        acc[b][0] = fmaf(e, pr[b][0], acc[b][0]);
        acc[b][1] = fmaf(e, pr[b][1], acc[b][1]);
        acc[b][2] = fmaf(e, pr[b][2], acc[b][2]);
        acc[b][3] = fmaf(e, pr[b][3], acc[b][3]);
      }
    }
  }
#pragma unroll
  for (int b = 0; b < BG; ++b) {
#pragma unroll
    for (int j = 0; j < 4; ++j) {
      float v = acc[b][j];
      v += __shfl_xor(v, 8);
      v += __shfl_xor(v, 16);
      v += __shfl_xor(v, 32);
      acc[b][j] = v;
    }
    if (MODE) {
      float v = lv[b];
      v += __shfl_xor(v, 8);
      v += __shfl_xor(v, 16);
      v += __shfl_xor(v, 32);
      lv[b] = v;
    }
  }
  const int lane = tid & 63;
  const int wv_id = tid >> 6;
  if ((lane >> 3) == 0) {
#pragma unroll
    for (int b = 0; b < BG; ++b) {
#pragma unroll
      for (int j = 0; j < 4; ++j) red[wv_id][dg][4 * b + j] = acc[b][j];
      if (MODE) red[wv_id][dg][16 + b] = lv[b];
    }
  }
  __syncthreads();
  if (tid < 128) {
    const int dgc = tid >> 4, e = tid & 15;
    float s = 0.f;
#pragma unroll
    for (int w = 0; w < 16; ++w) s += red[w][dgc][e];
    sS[e >> 2][4 * dgc + (e & 3)] = s;
  }
  if (MODE && tid >= 128 && tid < 128 + BG) {
    const int b = tid - 128;
    float s = 0.f;
#pragma unroll
    for (int w = 0; w < 16; ++w) s += red[w][0][16 + b];
    sL[b] = s;
  }
  __syncthreads();
}

__global__ __launch_bounds__(THREADS1, 4) void caps_route_kernel(
    const float* __restrict__ x, const float* __restrict__ W,
    float* __restrict__ out) {
  __shared__ float red[16][8][20];
  __shared__ float sS[BG][kD];
  __shared__ float sVec[BG][kD];
  __shared__ float sL[BG];
  const int i = blockIdx.x;
  const int xcd = i & 7;
  const int j = i >> 3;
  const int c = xcd + 8 * (j >> 3);
  const int b0 = 4 * (j & 7);
  const int tid = threadIdx.x;
  const int nslot = tid >> 3;
  const int dg = tid & 7;
  const float* Wc = W + (size_t)c * kN * kI * kD;
  sweep_pass<0>(Wc, x, b0, tid, nslot, dg, red, sS, sL, sVec);
  if (tid < BG) {
    const int b = tid;
    float sval[kD], sn = 0.f;
    const float inv = 1.0f / (float)kN;
#pragma unroll
    for (int d = 0; d < kD; ++d) {
      sval[d] = sS[b][d] * inv;
      sn += sval[d] * sval[d];
    }
    const float coef = sqrtf(sn) / (1.0f + sn);
#pragma unroll
    for (int d = 0; d < kD; ++d) sVec[b][d] = sval[d] * coef;
  }
  __syncthreads();
  sweep_pass<1>(Wc, x, b0, tid, nslot, dg, red, sS, sL, sVec);
  if (tid < BG) {
    const int b = tid;
    float sval[kD], sn = 0.f;
    const float inv = 1.0f / sL[b];
#pragma unroll
    for (int d = 0; d < kD; ++d) {
      sval[d] = sS[b][d] * inv;
      sn += sval[d] * sval[d];
    }
    const float coef = sqrtf(sn) / (1.0f + sn);
#pragma unroll
    for (int d = 0; d < kD; ++d) sVec[b][d] += sval[d] * coef;
  }
  __syncthreads();
  sweep_pass<1>(Wc, x, b0, tid, nslot, dg, red, sS, sL, sVec);
  if (tid < BG) {
    const int b = tid;
    float sval[kD], sn = 0.f;
    const float inv = 1.0f / sL[b];
#pragma unroll
    for (int d = 0; d < kD; ++d) {
      sval[d] = sS[b][d] * inv;
      sn += sval[d] * sval[d];
    }
    const float coef = sqrtf(sn) / (1.0f + sn);
    float* o = out + ((size_t)c * kB + (b0 + b)) * kD;
#pragma unroll
    for (int d = 0; d < kD; ++d) o[d] = sval[d] * coef;
  }
}
}  // namespace v1

// ---- mega gate: only a DEFINITIVE negative blocks the mega path -----------
// 0 = unknown (probe unavailable, e.g. under strict graph capture) -> MEGA.
// 1 = verified co-resident -> MEGA.  -1 = verified insufficient -> fallback.
namespace {
int g_mega_state = 0;
int probe_mega() {
  int dev = 0;
  if (hipGetDevice(&dev) != hipSuccess) return 0;
  int nCU = 0;
  if (hipDeviceGetAttribute(&nCU, hipDeviceAttributeMultiprocessorCount,
                            dev) != hipSuccess)
    return 0;
  int maxB = 0;
  if (hipOccupancyMaxActiveBlocksPerMultiprocessor(&maxB, k_mega3, 256, 0) !=
      hipSuccess)
    return 0;
  if (nCU <= 0 || maxB <= 0) return 0;
  return ((size_t)nCU * (size_t)maxB >= (size_t)GRID) ? 1 : -1;
}
struct MegaProbeInit {
  MegaProbeInit() {
    (void)hipFree(nullptr);  // force runtime init outside capture
    g_mega_state = probe_mega();
  }
} g_mega_probe_init;
}  // namespace

extern "C" void kernel_launch(void* const* d_in, const int* in_sizes, int n_in,
                              void* d_out, int out_size, void* d_ws,
                              size_t ws_size, hipStream_t stream) {
  const float* x = (const float*)d_in[0];  // [B,N,IN] fp32
  const float* W = (const float*)d_in[1];  // [C,N,IN,OUT] fp32
  float* out = (float*)d_out;              // [C,B,1,1,OUT] fp32
  (void)in_sizes; (void)n_in; (void)out_size;

  if (g_mega_state == 0) g_mega_state = probe_mega();  // retry if unknown

  if (g_mega_state >= 0 && ws_size >= WS_BYTES_MEGA) {
    _Float16* xt = (_Float16*)d_ws;
    _Float16* Wt = xt + XT_ELEMS;
    float* P = (float*)(Wt + WT_ELEMS);
    float* CVg = P + P_FLOATS;
    unsigned* bar = (unsigned*)(CVg + CV_FLOATS);  // zeroed by k_xt

    k_xt<<<GRID, 256, 0, stream>>>(x, xt, bar);
    k_mega3<<<GRID, 256, 0, stream>>>(W, xt, Wt, P, CVg, bar, out);
    return;
  }

  if (ws_size >= WS_BYTES_BIG) {
    _Float16* xt = (_Float16*)d_ws;
    _Float16* Wt = xt + XT_ELEMS;
    float* P = (float*)(Wt + WT_ELEMS);
    float* CV = P + P_FLOATS;

    k_xt<<<GRID, 256, 0, stream>>>(x, xt, nullptr);
    k_sweep<0, true><<<GRID, 256, 0, stream>>>(W, xt, nullptr, P, Wt);
    k_reduce<0><<<kC, 1024, 0, stream>>>(P, CV, nullptr);
    k_sweep_wt<<<GRID, 256, 0, stream>>>(Wt, xt, CV, P);
    k_reduce<1><<<kC, 1024, 0, stream>>>(P, CV, nullptr);
    k_sweep_wt<<<GRID, 256, 0, stream>>>(Wt, xt, CV, P);
    k_reduce<2><<<kC, 1024, 0, stream>>>(P, nullptr, out);
    return;
  }

  if (ws_size >= WS_BYTES_MID) {
    _Float16* xt = (_Float16*)d_ws;
    float* P = (float*)(xt + XT_ELEMS);
    float* CV = P + P_FLOATS;

    k_xt<<<GRID, 256, 0, stream>>>(x, xt, nullptr);
    k_sweep<0, false><<<GRID, 256, 0, stream>>>(W, xt, nullptr, P, nullptr);
    k_reduce<0><<<kC, 1024, 0, stream>>>(P, CV, nullptr);
    k_sweep<1, false><<<GRID, 256, 0, stream>>>(W, xt, CV, P, nullptr);
    k_reduce<1><<<kC, 1024, 0, stream>>>(P, CV, nullptr);
    k_sweep<1, false><<<GRID, 256, 0, stream>>>(W, xt, CV, P, nullptr);
    k_reduce<2><<<kC, 1024, 0, stream>>>(P, nullptr, out);
    return;
  }

  v1::caps_route_kernel<<<256, v1::THREADS1, 0, stream>>>(x, W, out);
}